// Round 4
// baseline (191.087 us; speedup 1.0000x reference)
//
#include <hip/hip_runtime.h>
#include <hip/hip_bf16.h>
#include <cstdint>

#define T_TOK 4096
#define D_DIM 1024
#define E_EXP 8
#define CAP   640          // int(1.25 * 4096 / 8)
#define NBIN  64
#define MAXDROP 3456
#define MT    10           // ceil(CAP/64) m-tiles per expert

typedef __attribute__((ext_vector_type(8))) short short8;
typedef __attribute__((ext_vector_type(4))) float f32x4;

// round-to-nearest-even float -> bf16 bits
__device__ inline unsigned short f2bf(float f) {
    uint32_t u = __float_as_uint(f);
    u += 0x7fffu + ((u >> 16) & 1u);
    return (unsigned short)(u >> 16);
}

// async global->LDS DMA, 16 B per lane. ldsptr is wave-uniform base; HW adds lane*16.
__device__ inline void dma16(const void* g, void* l) {
    __builtin_amdgcn_global_load_lds(
        (const __attribute__((address_space(1))) unsigned int*)g,
        (__attribute__((address_space(3))) unsigned int*)l, 16, 0, 0);
}

// ---------------- prep: [0,2048) W transpose-convert; [2048,3072) gating ----------------
__global__ __launch_bounds__(256) void prep_kernel(
    const float* __restrict__ x, const float* __restrict__ Wg,
    const float* __restrict__ bg, const float* __restrict__ W,
    unsigned short* __restrict__ xb, unsigned short* __restrict__ Wb,
    int* __restrict__ top_idx, float* __restrict__ top_prob, float* __restrict__ ppart)
{
    int bid = blockIdx.x;
    int tid = threadIdx.x;

    if (bid < 2048) {
        // ---- W[e][k][n] fp32 -> Wb[e][n][k] bf16, 64x64 tile via LDS ----
        __shared__ unsigned short tile[64][68];   // stride 68 shorts = 34 dwords (bank-spread)
        int e  = bid >> 8;
        int k0 = ((bid >> 4) & 15) * 64;
        int n0 = (bid & 15) * 64;
        const float* Wsrc = W + (size_t)e * D_DIM * D_DIM;
        #pragma unroll
        for (int p = 0; p < 4; p++) {
            int kk = p * 16 + (tid >> 4);
            int nn = (tid & 15) * 4;
            float4 v = *(const float4*)(Wsrc + (size_t)(k0 + kk) * D_DIM + n0 + nn);
            ushort4 u;
            u.x = f2bf(v.x); u.y = f2bf(v.y); u.z = f2bf(v.z); u.w = f2bf(v.w);
            *(ushort4*)&tile[kk][nn] = u;
        }
        __syncthreads();
        unsigned short* Wdst = Wb + (size_t)e * D_DIM * D_DIM;
        #pragma unroll
        for (int p = 0; p < 2; p++) {
            int n = p * 32 + (tid >> 3);
            int g = tid & 7;
            short8 v;
            #pragma unroll
            for (int z = 0; z < 8; z++) v[z] = (short)tile[g * 8 + z][n];
            *(short8*)&Wdst[(size_t)(n0 + n) * D_DIM + k0 + g * 8] = v;
        }
    } else {
        // ---- gating: 4 tokens/block, one wave/token; also emits bf16 xb ----
        int wid  = tid >> 6;
        int lane = tid & 63;
        int t = (bid - 2048) * 4 + wid;

        float acc[8];
        #pragma unroll
        for (int e = 0; e < 8; e++) acc[e] = 0.f;

        const float* xr = x + (size_t)t * D_DIM;
        #pragma unroll
        for (int i = 0; i < 4; i++) {
            int d0 = i * 256 + lane * 4;
            float4 xv = *(const float4*)(xr + d0);
            ushort4 u;
            u.x = f2bf(xv.x); u.y = f2bf(xv.y); u.z = f2bf(xv.z); u.w = f2bf(xv.w);
            *(ushort4*)&xb[(size_t)t * D_DIM + d0] = u;
            float xs[4] = {xv.x, xv.y, xv.z, xv.w};
            #pragma unroll
            for (int j = 0; j < 4; j++) {
                const float4* wr = (const float4*)(Wg + (size_t)(d0 + j) * 8);
                float4 w0 = wr[0], w1 = wr[1];
                acc[0] += xs[j] * w0.x; acc[1] += xs[j] * w0.y;
                acc[2] += xs[j] * w0.z; acc[3] += xs[j] * w0.w;
                acc[4] += xs[j] * w1.x; acc[5] += xs[j] * w1.y;
                acc[6] += xs[j] * w1.z; acc[7] += xs[j] * w1.w;
            }
        }
        #pragma unroll
        for (int off = 32; off > 0; off >>= 1) {
            #pragma unroll
            for (int e = 0; e < 8; e++) acc[e] += __shfl_xor(acc[e], off, 64);
        }
        if (lane == 0) {
            float lg[8];
            #pragma unroll
            for (int e = 0; e < 8; e++) lg[e] = acc[e] + bg[e];
            float m = lg[0]; int am = 0;
            #pragma unroll
            for (int e = 1; e < 8; e++) { if (lg[e] > m) { m = lg[e]; am = e; } }
            float ex[8], s = 0.f;
            #pragma unroll
            for (int e = 0; e < 8; e++) { ex[e] = expf(lg[e] - m); s += ex[e]; }
            float inv = 1.f / s;
            top_idx[t]  = am;
            top_prob[t] = ex[am] * inv;
            int bin = (int)(bid & (NBIN - 1));
            #pragma unroll
            for (int e = 0; e < 8; e++) atomicAdd(&ppart[bin * 8 + e], ex[e] * inv);
        }
    }
}

// ---------------- scan: hierarchical capacity dispatch, 1 block x 1024 thr ----------------
__global__ __launch_bounds__(1024) void scan_kernel(
    const int* __restrict__ top_idx,
    int* __restrict__ tok_list, int* __restrict__ cnt, int* __restrict__ fullcnt,
    float* __restrict__ out)
{
    __shared__ int counts[64][8];
    __shared__ int excl[64][8];
    __shared__ int droplist[MAXDROP];
    __shared__ int ndrop;

    int tid  = threadIdx.x;
    int wv   = tid >> 6;
    int lane = tid & 63;
    unsigned long long ltmask = (lane == 0) ? 0ull : ((~0ull) >> (64 - lane));

    if (tid == 0) ndrop = 0;

    int ecache[4];
    #pragma unroll
    for (int c = 0; c < 4; c++)
        ecache[c] = top_idx[(4 * wv + c) * 64 + lane];

    #pragma unroll
    for (int c = 0; c < 4; c++) {
        int chunk = 4 * wv + c;
        int e = ecache[c];
        #pragma unroll
        for (int q = 0; q < 8; q++) {
            unsigned long long mk = __ballot(e == q);
            int tot = __popcll(mk);
            if (lane == q) counts[chunk][q] = tot;
        }
    }
    __syncthreads();

    if (wv == 0) {
        #pragma unroll
        for (int q = 0; q < 8; q++) {
            int v = counts[lane][q];
            int orig = v;
            #pragma unroll
            for (int off = 1; off < 64; off <<= 1) {
                int n = __shfl_up(v, off, 64);
                if (lane >= off) v += n;
            }
            excl[lane][q] = v - orig;
            int total = __shfl(v, 63, 64);
            if (lane == 0) {
                fullcnt[q] = total;
                cnt[q] = total < CAP ? total : CAP;
            }
        }
    }
    __syncthreads();

    #pragma unroll
    for (int c = 0; c < 4; c++) {
        int chunk = 4 * wv + c;
        int t = chunk * 64 + lane;
        int e = ecache[c];
        int pos = 0;
        #pragma unroll
        for (int q = 0; q < 8; q++) {
            unsigned long long mk = __ballot(e == q);
            if (e == q) pos = excl[chunk][q] + __popcll(mk & ltmask);
        }
        if (pos < CAP) {
            tok_list[e * CAP + pos] = t;
        } else {
            int di = atomicAdd(&ndrop, 1);
            droplist[di] = t;
        }
    }
    __syncthreads();

    int nd = ndrop;
    int grp = tid >> 8;
    int col = (tid & 255) * 4;
    float4 z = {0.f, 0.f, 0.f, 0.f};
    for (int d = grp; d < nd; d += 4) {
        int row = droplist[d];
        *(float4*)&out[(size_t)row * D_DIM + col] = z;
    }
}

// ---------------- expert GEMM: 64x64x64 tiles, DMA-staged bf16, dbuf LDS ----------------
__device__ inline void stage_dma(const unsigned short* gA, const unsigned short* gB,
                                 unsigned short (*Ab)[64][8], unsigned short (*Bb)[64][8],
                                 int k0, int w)
{
    dma16(gA + k0 + w * 8,       &Ab[w][0][0]);
    dma16(gA + k0 + (w + 4) * 8, &Ab[w + 4][0][0]);
    dma16(gB + k0 + w * 8,       &Bb[w][0][0]);
    dma16(gB + k0 + (w + 4) * 8, &Bb[w + 4][0][0]);
}

__global__ __launch_bounds__(256) void expert_gemm(
    const unsigned short* __restrict__ xb, const unsigned short* __restrict__ Wb,
    const float* __restrict__ bias,
    const int* __restrict__ tok_list, const int* __restrict__ cnt,
    const float* __restrict__ top_prob, float* __restrict__ out)
{
    int bid = blockIdx.x;
    int e   = bid / (MT * 16);
    int rem = bid % (MT * 16);
    int mt  = rem >> 4, nt = rem & 15;
    int count = cnt[e];
    int m0 = mt * 64;
    if (m0 >= count) return;
    int n0 = nt * 64;

    // [buf][kgroup][row][8 bf16]: group-plane stride 1024 B == 0 mod 32 banks,
    // row stride 16 B -> banks depend only on row -> 2-way aliasing (free).
    __shared__ unsigned short Ab[2][8][64][8];   // 16 KB
    __shared__ unsigned short Bb[2][8][64][8];   // 16 KB

    int tid  = threadIdx.x;
    int lane = tid & 63, w = tid >> 6;
    int quad = lane >> 4, l16 = lane & 15;
    int mw = (w >> 1) * 32, nw = (w & 1) * 32;

    const int* tl = tok_list + e * CAP;
    int ra = m0 + lane; if (ra >= count) ra = count - 1;
    int tokA = tl[ra];
    const unsigned short* gA = xb + (size_t)tokA * D_DIM;
    const unsigned short* gB = Wb + (size_t)e * D_DIM * D_DIM + (size_t)(n0 + lane) * D_DIM;

    f32x4 acc[2][2];
    #pragma unroll
    for (int i = 0; i < 2; i++)
        #pragma unroll
        for (int j = 0; j < 2; j++)
            acc[i][j] = (f32x4){0.f, 0.f, 0.f, 0.f};

    stage_dma(gA, gB, Ab[0], Bb[0], 0, w);

    int cur = 0;
    #pragma unroll 1
    for (int kt = 0; kt < 16; kt++) {
        __syncthreads();                         // drains DMA for cur (vmcnt) + LDS
        if (kt + 1 < 16)
            stage_dma(gA, gB, Ab[cur ^ 1], Bb[cur ^ 1], (kt + 1) * 64, w);

        short8 af[2][2], bf[2][2];               // [s][i]
        #pragma unroll
        for (int s = 0; s < 2; s++) {
            #pragma unroll
            for (int i = 0; i < 2; i++) {
                af[s][i] = *(const short8*)&Ab[cur][s * 4 + quad][mw + 16 * i + l16][0];
                bf[s][i] = *(const short8*)&Bb[cur][s * 4 + quad][nw + 16 * i + l16][0];
            }
        }
        #pragma unroll
        for (int s = 0; s < 2; s++)
            #pragma unroll
            for (int i = 0; i < 2; i++)
                #pragma unroll
                for (int j = 0; j < 2; j++)
                    acc[i][j] = __builtin_amdgcn_mfma_f32_16x16x32_bf16(
                        af[s][i], bf[s][j], acc[i][j], 0, 0, 0);
        cur ^= 1;
    }

    float bv[2];
    #pragma unroll
    for (int j = 0; j < 2; j++)
        bv[j] = bias[e * D_DIM + n0 + nw + 16 * j + l16];

    #pragma unroll
    for (int i = 0; i < 2; i++) {
        int rb = m0 + mw + 16 * i + quad * 4;
        #pragma unroll
        for (int r = 0; r < 4; r++) {
            int gm = rb + r;
            if (gm >= count) continue;
            int tok = tl[gm];
            float p = top_prob[tok];
            float* orow = out + (size_t)tok * D_DIM + n0 + nw + l16;
            #pragma unroll
            for (int j = 0; j < 2; j++)
                orow[16 * j] = (acc[i][j][r] + bv[j]) * p;
        }
    }
}

// ---------------- aux loss ----------------
__global__ void aux_kernel(const float* __restrict__ ppart, const int* __restrict__ fullcnt,
                           float* __restrict__ out_aux) {
    int lane = threadIdx.x;           // 64 = NBIN
    float p[8];
    #pragma unroll
    for (int e = 0; e < 8; e++) p[e] = ppart[lane * 8 + e];
    #pragma unroll
    for (int off = 32; off > 0; off >>= 1) {
        #pragma unroll
        for (int e = 0; e < 8; e++) p[e] += __shfl_xor(p[e], off, 64);
    }
    if (lane == 0) {
        float s = 0.f;
        #pragma unroll
        for (int e = 0; e < 8; e++)
            s += ((float)fullcnt[e] / (float)T_TOK) * (p[e] / (float)T_TOK);
        out_aux[0] = (float)E_EXP * s;
    }
}

extern "C" void kernel_launch(void* const* d_in, const int* in_sizes, int n_in,
                              void* d_out, int out_size, void* d_ws, size_t ws_size,
                              hipStream_t stream) {
    const float* x  = (const float*)d_in[0];   // [4096,1024]
    const float* Wg = (const float*)d_in[1];   // [1024,8]
    const float* bg = (const float*)d_in[2];   // [8]
    const float* W  = (const float*)d_in[3];   // [8,1024,1024]
    const float* b  = (const float*)d_in[4];   // [8,1024]
    float* out = (float*)d_out;                // [4096*1024 + 1]

    char* ws = (char*)d_ws;                    // ~24.1 MB used
    unsigned short* xb = (unsigned short*)(ws + 0);          // 8,388,608 B
    unsigned short* Wb = (unsigned short*)(ws + 8388608);    // 16,777,216 B
    int*   top_idx  = (int*)(ws + 25165824);   // 16384 B
    float* top_prob = (float*)(ws + 25182208); // 16384 B
    int*   tok_list = (int*)(ws + 25198592);   // 20480 B
    int*   cnt      = (int*)(ws + 25219072);   // 32 B
    int*   fullcnt  = (int*)(ws + 25219104);   // 32 B
    float* ppart    = (float*)(ws + 25219136); // 2048 B

    hipMemsetAsync(ppart, 0, NBIN * 8 * sizeof(float), stream);
    hipLaunchKernelGGL(prep_kernel, dim3(2048 + T_TOK / 4), dim3(256), 0, stream,
                       x, Wg, bg, W, xb, Wb, top_idx, top_prob, ppart);
    hipLaunchKernelGGL(scan_kernel, dim3(1), dim3(1024), 0, stream,
                       top_idx, tok_list, cnt, fullcnt, out);
    hipLaunchKernelGGL(expert_gemm, dim3(E_EXP * MT * 16), dim3(256), 0, stream,
                       xb, Wb, b, tok_list, cnt, top_prob, out);
    hipLaunchKernelGGL(aux_kernel, dim3(1), dim3(64), 0, stream, ppart, fullcnt,
                       out + (size_t)T_TOK * D_DIM);
}

// Round 5
// 180.738 us; speedup vs baseline: 1.0573x; 1.0573x over previous
//
#include <hip/hip_runtime.h>
#include <hip/hip_bf16.h>
#include <cstdint>

#define T_TOK 4096
#define D_DIM 1024
#define E_EXP 8
#define CAP   640          // int(1.25 * 4096 / 8)
#define NBIN  64
#define MAXDROP 3456
#define MT    10           // ceil(CAP/64) m-tiles per expert

typedef __attribute__((ext_vector_type(8))) short short8;
typedef __attribute__((ext_vector_type(4))) float f32x4;

// round-to-nearest-even float -> bf16 bits
__device__ inline unsigned short f2bf(float f) {
    uint32_t u = __float_as_uint(f);
    u += 0x7fffu + ((u >> 16) & 1u);
    return (unsigned short)(u >> 16);
}

// async global->LDS DMA, 16 B per lane. ldsptr is wave-uniform base; HW adds lane*16.
__device__ inline void dma16(const void* g, void* l) {
    __builtin_amdgcn_global_load_lds(
        (const __attribute__((address_space(1))) unsigned int*)g,
        (__attribute__((address_space(3))) unsigned int*)l, 16, 0, 0);
}

// ---------------- prep: [0,2048) W transpose-convert; [2048,3072) gating ----------------
__global__ __launch_bounds__(256) void prep_kernel(
    const float* __restrict__ x, const float* __restrict__ Wg,
    const float* __restrict__ bg, const float* __restrict__ W,
    unsigned short* __restrict__ xb, unsigned short* __restrict__ Wb,
    int* __restrict__ top_idx, float* __restrict__ top_prob, float* __restrict__ ppart)
{
    int bid = blockIdx.x;
    int tid = threadIdx.x;

    if (bid < 2048) {
        // ---- W[e][k][n] fp32 -> Wb[e][n][k] bf16, 64x64 tile via LDS ----
        // stride 66 shorts = 33 dwords: bank period 32 -> both phases ~2-way (free)
        __shared__ unsigned short tile[64][66];
        int e  = bid >> 8;
        int k0 = ((bid >> 4) & 15) * 64;
        int n0 = (bid & 15) * 64;
        const float* Wsrc = W + (size_t)e * D_DIM * D_DIM;
        #pragma unroll
        for (int p = 0; p < 4; p++) {
            int kk = p * 16 + (tid >> 4);
            int nn = (tid & 15) * 4;
            float4 v = *(const float4*)(Wsrc + (size_t)(k0 + kk) * D_DIM + n0 + nn);
            ushort4 u;
            u.x = f2bf(v.x); u.y = f2bf(v.y); u.z = f2bf(v.z); u.w = f2bf(v.w);
            *(ushort4*)&tile[kk][nn] = u;
        }
        __syncthreads();
        unsigned short* Wdst = Wb + (size_t)e * D_DIM * D_DIM;
        #pragma unroll
        for (int p = 0; p < 2; p++) {
            int n = p * 32 + (tid >> 3);
            int g = tid & 7;
            short8 v;
            #pragma unroll
            for (int z = 0; z < 8; z++) v[z] = (short)tile[g * 8 + z][n];
            *(short8*)&Wdst[(size_t)(n0 + n) * D_DIM + k0 + g * 8] = v;
        }
    } else {
        // ---- gating: 4 tokens/block, one wave/token; Wg transposed in LDS ----
        __shared__ float WgT[8][1024];   // 32 KB
        #pragma unroll
        for (int r = 0; r < 4; r++) {
            int d = tid + 256 * r;
            const float4* wr = (const float4*)(Wg + (size_t)d * 8);
            float4 a = wr[0], bq = wr[1];
            WgT[0][d] = a.x;  WgT[1][d] = a.y;  WgT[2][d] = a.z;  WgT[3][d] = a.w;
            WgT[4][d] = bq.x; WgT[5][d] = bq.y; WgT[6][d] = bq.z; WgT[7][d] = bq.w;
        }
        __syncthreads();

        int wid  = tid >> 6;
        int lane = tid & 63;
        int t = (bid - 2048) * 4 + wid;

        const float* xr = x + (size_t)t * D_DIM;
        unsigned short* xrow = xb + (size_t)t * D_DIM;

        float acc[8];
        #pragma unroll
        for (int e = 0; e < 8; e++) acc[e] = 0.f;

        #pragma unroll
        for (int ii = 0; ii < 8; ii++) {
            int da = lane + 128 * ii;
            int db = da + 64;
            float xa = xr[da];
            float xc = xr[db];
            xrow[da] = f2bf(xa);
            xrow[db] = f2bf(xc);
            #pragma unroll
            for (int e = 0; e < 8; e++)
                acc[e] += xa * WgT[e][da] + xc * WgT[e][db];   // ds_read2_b32 pairs
        }
        #pragma unroll
        for (int off = 32; off > 0; off >>= 1) {
            #pragma unroll
            for (int e = 0; e < 8; e++) acc[e] += __shfl_xor(acc[e], off, 64);
        }
        if (lane == 0) {
            float lg[8];
            #pragma unroll
            for (int e = 0; e < 8; e++) lg[e] = acc[e] + bg[e];
            float m = lg[0]; int am = 0;
            #pragma unroll
            for (int e = 1; e < 8; e++) { if (lg[e] > m) { m = lg[e]; am = e; } }
            float ex[8], s = 0.f;
            #pragma unroll
            for (int e = 0; e < 8; e++) { ex[e] = expf(lg[e] - m); s += ex[e]; }
            float inv = 1.f / s;
            top_idx[t]  = am;
            top_prob[t] = ex[am] * inv;
            int bin = (int)(bid & (NBIN - 1));
            #pragma unroll
            for (int e = 0; e < 8; e++) atomicAdd(&ppart[bin * 8 + e], ex[e] * inv);
        }
    }
}

// ---------------- scan: hierarchical capacity dispatch, 1 block x 1024 thr ----------------
__global__ __launch_bounds__(1024) void scan_kernel(
    const int* __restrict__ top_idx,
    int* __restrict__ tok_list, int* __restrict__ cnt, int* __restrict__ fullcnt,
    float* __restrict__ out)
{
    __shared__ int counts[64][8];
    __shared__ int excl[64][8];
    __shared__ int droplist[MAXDROP];
    __shared__ int ndrop;

    int tid  = threadIdx.x;
    int wv   = tid >> 6;
    int lane = tid & 63;
    unsigned long long ltmask = (lane == 0) ? 0ull : ((~0ull) >> (64 - lane));

    if (tid == 0) ndrop = 0;

    int ecache[4];
    #pragma unroll
    for (int c = 0; c < 4; c++)
        ecache[c] = top_idx[(4 * wv + c) * 64 + lane];

    #pragma unroll
    for (int c = 0; c < 4; c++) {
        int chunk = 4 * wv + c;
        int e = ecache[c];
        #pragma unroll
        for (int q = 0; q < 8; q++) {
            unsigned long long mk = __ballot(e == q);
            int tot = __popcll(mk);
            if (lane == q) counts[chunk][q] = tot;
        }
    }
    __syncthreads();

    if (wv == 0) {
        #pragma unroll
        for (int q = 0; q < 8; q++) {
            int v = counts[lane][q];
            int orig = v;
            #pragma unroll
            for (int off = 1; off < 64; off <<= 1) {
                int n = __shfl_up(v, off, 64);
                if (lane >= off) v += n;
            }
            excl[lane][q] = v - orig;
            int total = __shfl(v, 63, 64);
            if (lane == 0) {
                fullcnt[q] = total;
                cnt[q] = total < CAP ? total : CAP;
            }
        }
    }
    __syncthreads();

    #pragma unroll
    for (int c = 0; c < 4; c++) {
        int chunk = 4 * wv + c;
        int t = chunk * 64 + lane;
        int e = ecache[c];
        int pos = 0;
        #pragma unroll
        for (int q = 0; q < 8; q++) {
            unsigned long long mk = __ballot(e == q);
            if (e == q) pos = excl[chunk][q] + __popcll(mk & ltmask);
        }
        if (pos < CAP) {
            tok_list[e * CAP + pos] = t;
        } else {
            int di = atomicAdd(&ndrop, 1);
            droplist[di] = t;
        }
    }
    __syncthreads();

    int nd = ndrop;
    int grp = tid >> 8;
    int col = (tid & 255) * 4;
    float4 z = {0.f, 0.f, 0.f, 0.f};
    for (int d = grp; d < nd; d += 4) {
        int row = droplist[d];
        *(float4*)&out[(size_t)row * D_DIM + col] = z;
    }
}

// ---------------- expert GEMM: 64x64x64 tiles, DMA-staged bf16, dbuf LDS ----------------
__device__ inline void stage_dma(const unsigned short* gA, const unsigned short* gB,
                                 unsigned short (*Ab)[64][8], unsigned short (*Bb)[64][8],
                                 int k0, int w)
{
    dma16(gA + k0 + w * 8,       &Ab[w][0][0]);
    dma16(gA + k0 + (w + 4) * 8, &Ab[w + 4][0][0]);
    dma16(gB + k0 + w * 8,       &Bb[w][0][0]);
    dma16(gB + k0 + (w + 4) * 8, &Bb[w + 4][0][0]);
}

__global__ __launch_bounds__(256) void expert_gemm(
    const unsigned short* __restrict__ xb, const unsigned short* __restrict__ Wb,
    const float* __restrict__ bias,
    const int* __restrict__ tok_list, const int* __restrict__ cnt,
    const float* __restrict__ top_prob, float* __restrict__ out)
{
    int bid = blockIdx.x;
    int e   = bid / (MT * 16);
    int rem = bid % (MT * 16);
    int mt  = rem >> 4, nt = rem & 15;
    int count = cnt[e];
    int m0 = mt * 64;
    if (m0 >= count) return;
    int n0 = nt * 64;

    // [buf][kgroup][row][8 bf16]: group-plane stride 1024 B == 0 mod 32 banks,
    // row stride 16 B -> banks depend only on row -> 2-way aliasing (free).
    __shared__ unsigned short Ab[2][8][64][8];   // 16 KB
    __shared__ unsigned short Bb[2][8][64][8];   // 16 KB

    int tid  = threadIdx.x;
    int lane = tid & 63, w = tid >> 6;
    int quad = lane >> 4, l16 = lane & 15;
    int mw = (w >> 1) * 32, nw = (w & 1) * 32;

    const int* tl = tok_list + e * CAP;
    int ra = m0 + lane; if (ra >= count) ra = count - 1;
    int tokA = tl[ra];
    const unsigned short* gA = xb + (size_t)tokA * D_DIM;
    const unsigned short* gB = Wb + (size_t)e * D_DIM * D_DIM + (size_t)(n0 + lane) * D_DIM;

    f32x4 acc[2][2];
    #pragma unroll
    for (int i = 0; i < 2; i++)
        #pragma unroll
        for (int j = 0; j < 2; j++)
            acc[i][j] = (f32x4){0.f, 0.f, 0.f, 0.f};

    stage_dma(gA, gB, Ab[0], Bb[0], 0, w);

    int cur = 0;
    #pragma unroll 1
    for (int kt = 0; kt < 16; kt++) {
        __syncthreads();                         // drains DMA for cur (vmcnt) + LDS
        if (kt + 1 < 16)
            stage_dma(gA, gB, Ab[cur ^ 1], Bb[cur ^ 1], (kt + 1) * 64, w);

        short8 af[2][2], bf[2][2];               // [s][i]
        #pragma unroll
        for (int s = 0; s < 2; s++) {
            #pragma unroll
            for (int i = 0; i < 2; i++) {
                af[s][i] = *(const short8*)&Ab[cur][s * 4 + quad][mw + 16 * i + l16][0];
                bf[s][i] = *(const short8*)&Bb[cur][s * 4 + quad][nw + 16 * i + l16][0];
            }
        }
        #pragma unroll
        for (int s = 0; s < 2; s++)
            #pragma unroll
            for (int i = 0; i < 2; i++)
                #pragma unroll
                for (int j = 0; j < 2; j++)
                    acc[i][j] = __builtin_amdgcn_mfma_f32_16x16x32_bf16(
                        af[s][i], bf[s][j], acc[i][j], 0, 0, 0);
        cur ^= 1;
    }

    float bv[2];
    #pragma unroll
    for (int j = 0; j < 2; j++)
        bv[j] = bias[e * D_DIM + n0 + nw + 16 * j + l16];

    #pragma unroll
    for (int i = 0; i < 2; i++) {
        int rb = m0 + mw + 16 * i + quad * 4;
        #pragma unroll
        for (int r = 0; r < 4; r++) {
            int gm = rb + r;
            if (gm >= count) continue;
            int tok = tl[gm];
            float p = top_prob[tok];
            float* orow = out + (size_t)tok * D_DIM + n0 + nw + l16;
            #pragma unroll
            for (int j = 0; j < 2; j++)
                orow[16 * j] = (acc[i][j][r] + bv[j]) * p;
        }
    }
}

// ---------------- aux loss ----------------
__global__ void aux_kernel(const float* __restrict__ ppart, const int* __restrict__ fullcnt,
                           float* __restrict__ out_aux) {
    int lane = threadIdx.x;           // 64 = NBIN
    float p[8];
    #pragma unroll
    for (int e = 0; e < 8; e++) p[e] = ppart[lane * 8 + e];
    #pragma unroll
    for (int off = 32; off > 0; off >>= 1) {
        #pragma unroll
        for (int e = 0; e < 8; e++) p[e] += __shfl_xor(p[e], off, 64);
    }
    if (lane == 0) {
        float s = 0.f;
        #pragma unroll
        for (int e = 0; e < 8; e++)
            s += ((float)fullcnt[e] / (float)T_TOK) * (p[e] / (float)T_TOK);
        out_aux[0] = (float)E_EXP * s;
    }
}

extern "C" void kernel_launch(void* const* d_in, const int* in_sizes, int n_in,
                              void* d_out, int out_size, void* d_ws, size_t ws_size,
                              hipStream_t stream) {
    const float* x  = (const float*)d_in[0];   // [4096,1024]
    const float* Wg = (const float*)d_in[1];   // [1024,8]
    const float* bg = (const float*)d_in[2];   // [8]
    const float* W  = (const float*)d_in[3];   // [8,1024,1024]
    const float* b  = (const float*)d_in[4];   // [8,1024]
    float* out = (float*)d_out;                // [4096*1024 + 1]

    char* ws = (char*)d_ws;                    // ~24.1 MB used
    unsigned short* xb = (unsigned short*)(ws + 0);          // 8,388,608 B
    unsigned short* Wb = (unsigned short*)(ws + 8388608);    // 16,777,216 B
    int*   top_idx  = (int*)(ws + 25165824);   // 16384 B
    float* top_prob = (float*)(ws + 25182208); // 16384 B
    int*   tok_list = (int*)(ws + 25198592);   // 20480 B
    int*   cnt      = (int*)(ws + 25219072);   // 32 B
    int*   fullcnt  = (int*)(ws + 25219104);   // 32 B
    float* ppart    = (float*)(ws + 25219136); // 2048 B

    hipMemsetAsync(ppart, 0, NBIN * 8 * sizeof(float), stream);
    hipLaunchKernelGGL(prep_kernel, dim3(2048 + T_TOK / 4), dim3(256), 0, stream,
                       x, Wg, bg, W, xb, Wb, top_idx, top_prob, ppart);
    hipLaunchKernelGGL(scan_kernel, dim3(1), dim3(1024), 0, stream,
                       top_idx, tok_list, cnt, fullcnt, out);
    hipLaunchKernelGGL(expert_gemm, dim3(E_EXP * MT * 16), dim3(256), 0, stream,
                       xb, Wb, b, tok_list, cnt, top_prob, out);
    hipLaunchKernelGGL(aux_kernel, dim3(1), dim3(64), 0, stream, ppart, fullcnt,
                       out + (size_t)T_TOK * D_DIM);
}

// Round 7
// 166.941 us; speedup vs baseline: 1.1446x; 1.0826x over previous
//
#include <hip/hip_runtime.h>
#include <hip/hip_bf16.h>
#include <cstdint>

#define T_TOK 4096
#define D_DIM 1024
#define E_EXP 8
#define CAP   640          // int(1.25 * 4096 / 8)
#define NBIN  64
#define MAXDROP 3456
#define MT    10           // ceil(CAP/64) m-tiles per expert

typedef __attribute__((ext_vector_type(8))) short short8;
typedef __attribute__((ext_vector_type(4))) float f32x4;

// round-to-nearest-even float -> bf16 bits
__device__ inline unsigned short f2bf(float f) {
    uint32_t u = __float_as_uint(f);
    u += 0x7fffu + ((u >> 16) & 1u);
    return (unsigned short)(u >> 16);
}

// async global->LDS DMA: per-lane global address (g is this lane's 16-B slice),
// wave-uniform LDS base; HW writes lane's data at ldsbase + lane*16.
__device__ inline void dma16(const void* g, void* l) {
    __builtin_amdgcn_global_load_lds(
        (const __attribute__((address_space(1))) unsigned int*)g,
        (__attribute__((address_space(3))) unsigned int*)l, 16, 0, 0);
}

// tile base in tiled bf16 image: planes g=0..7, each [64 rows][8 shorts] = 1 KB
#define WB_TILE(e, nt, kt) ((((size_t)(e) * 16 + (nt)) * 16 + (kt)) * 4096)
#define XG_TILE(e, mt, kt) ((((size_t)(e) * MT + (mt)) * 16 + (kt)) * 4096)

// ---------------- prep: [0,2048) W transpose-convert to tiled Wb; [2048,3072) gating ----------------
__global__ __launch_bounds__(256) void prep_kernel(
    const float* __restrict__ x, const float* __restrict__ Wg,
    const float* __restrict__ bg, const float* __restrict__ W,
    unsigned short* __restrict__ Wb,
    int* __restrict__ top_idx, float* __restrict__ top_prob, float* __restrict__ ppart)
{
    int bid = blockIdx.x;
    int tid = threadIdx.x;

    if (bid < 2048) {
        // ---- W[e][k][n] fp32 -> Wb tiled [e][nt][kt][g][n][8] bf16 ----
        __shared__ unsigned short tile[64][66];   // stride 66 shorts: ~2-way banks (free)
        int e  = bid >> 8;
        int kt = (bid >> 4) & 15;
        int nt = bid & 15;
        int k0 = kt * 64, n0 = nt * 64;
        const float* Wsrc = W + (size_t)e * D_DIM * D_DIM;
        #pragma unroll
        for (int p = 0; p < 4; p++) {
            int kk = p * 16 + (tid >> 4);
            int nn = (tid & 15) * 4;
            float4 v = *(const float4*)(Wsrc + (size_t)(k0 + kk) * D_DIM + n0 + nn);
            ushort4 u;
            u.x = f2bf(v.x); u.y = f2bf(v.y); u.z = f2bf(v.z); u.w = f2bf(v.w);
            *(ushort4*)&tile[kk][nn] = u;
        }
        __syncthreads();
        unsigned short* dst = Wb + WB_TILE(e, nt, kt);
        #pragma unroll
        for (int p = 0; p < 2; p++) {
            int c = tid + 256 * p;        // chunk = g*64 + n
            int g = c >> 6, n = c & 63;
            short8 v;
            #pragma unroll
            for (int z = 0; z < 8; z++) v[z] = (short)tile[g * 8 + z][n];
            *(short8*)&dst[(size_t)c * 8] = v;   // fully coalesced
        }
    } else {
        // ---- gating: 4 tokens/block, one wave/token; Wg transposed in LDS ----
        __shared__ float WgT[8][1024];   // 32 KB
        #pragma unroll
        for (int r = 0; r < 4; r++) {
            int d = tid + 256 * r;
            const float4* wr = (const float4*)(Wg + (size_t)d * 8);
            float4 a = wr[0], bq = wr[1];
            WgT[0][d] = a.x;  WgT[1][d] = a.y;  WgT[2][d] = a.z;  WgT[3][d] = a.w;
            WgT[4][d] = bq.x; WgT[5][d] = bq.y; WgT[6][d] = bq.z; WgT[7][d] = bq.w;
        }
        __syncthreads();

        int wid  = tid >> 6;
        int lane = tid & 63;
        int t = (bid - 2048) * 4 + wid;

        const float* xr = x + (size_t)t * D_DIM;

        float acc[8];
        #pragma unroll
        for (int e = 0; e < 8; e++) acc[e] = 0.f;

        #pragma unroll
        for (int ii = 0; ii < 8; ii++) {
            int da = lane + 128 * ii;
            int db = da + 64;
            float xa = xr[da];
            float xc = xr[db];
            #pragma unroll
            for (int e = 0; e < 8; e++)
                acc[e] += xa * WgT[e][da] + xc * WgT[e][db];
        }
        #pragma unroll
        for (int off = 32; off > 0; off >>= 1) {
            #pragma unroll
            for (int e = 0; e < 8; e++) acc[e] += __shfl_xor(acc[e], off, 64);
        }
        if (lane == 0) {
            float lg[8];
            #pragma unroll
            for (int e = 0; e < 8; e++) lg[e] = acc[e] + bg[e];
            float m = lg[0]; int am = 0;
            #pragma unroll
            for (int e = 1; e < 8; e++) { if (lg[e] > m) { m = lg[e]; am = e; } }
            float ex[8], s = 0.f;
            #pragma unroll
            for (int e = 0; e < 8; e++) { ex[e] = expf(lg[e] - m); s += ex[e]; }
            float inv = 1.f / s;
            top_idx[t]  = am;
            top_prob[t] = ex[am] * inv;
            int bin = (int)(bid & (NBIN - 1));
            #pragma unroll
            for (int e = 0; e < 8; e++) atomicAdd(&ppart[bin * 8 + e], ex[e] * inv);
        }
    }
}

// ---------------- scan: capacity dispatch + aux loss, 1 block x 1024 thr ----------------
__global__ __launch_bounds__(1024) void scan_kernel(
    const int* __restrict__ top_idx,
    int* __restrict__ tok_list, int* __restrict__ cnt,
    const float* __restrict__ ppart,
    float* __restrict__ out, float* __restrict__ out_aux)
{
    __shared__ int counts[64][8];
    __shared__ int excl[64][8];
    __shared__ int fulltot[8];
    __shared__ int droplist[MAXDROP];
    __shared__ int ndrop;

    int tid  = threadIdx.x;
    int wv   = tid >> 6;
    int lane = tid & 63;
    unsigned long long ltmask = (lane == 0) ? 0ull : ((~0ull) >> (64 - lane));

    if (tid == 0) ndrop = 0;

    int ecache[4];
    #pragma unroll
    for (int c = 0; c < 4; c++)
        ecache[c] = top_idx[(4 * wv + c) * 64 + lane];

    #pragma unroll
    for (int c = 0; c < 4; c++) {
        int chunk = 4 * wv + c;
        int e = ecache[c];
        #pragma unroll
        for (int q = 0; q < 8; q++) {
            unsigned long long mk = __ballot(e == q);
            int tot = __popcll(mk);
            if (lane == q) counts[chunk][q] = tot;
        }
    }
    __syncthreads();

    if (wv == 0) {
        #pragma unroll
        for (int q = 0; q < 8; q++) {
            int v = counts[lane][q];
            int orig = v;
            #pragma unroll
            for (int off = 1; off < 64; off <<= 1) {
                int n = __shfl_up(v, off, 64);
                if (lane >= off) v += n;
            }
            excl[lane][q] = v - orig;
            int total = __shfl(v, 63, 64);
            if (lane == 0) {
                fulltot[q] = total;
                cnt[q] = total < CAP ? total : CAP;
            }
        }
    }
    __syncthreads();

    #pragma unroll
    for (int c = 0; c < 4; c++) {
        int chunk = 4 * wv + c;
        int t = chunk * 64 + lane;
        int e = ecache[c];
        int pos = 0;
        #pragma unroll
        for (int q = 0; q < 8; q++) {
            unsigned long long mk = __ballot(e == q);
            if (e == q) pos = excl[chunk][q] + __popcll(mk & ltmask);
        }
        if (pos < CAP) {
            tok_list[e * CAP + pos] = t;
        } else {
            int di = atomicAdd(&ndrop, 1);
            droplist[di] = t;
        }
    }
    __syncthreads();

    // zero dropped rows (usually none)
    int nd = ndrop;
    int grp = tid >> 8;
    int col = (tid & 255) * 4;
    float4 z = {0.f, 0.f, 0.f, 0.f};
    for (int d = grp; d < nd; d += 4) {
        int row = droplist[d];
        *(float4*)&out[(size_t)row * D_DIM + col] = z;
    }

    // aux loss (wave 0): E * sum_e (fullcnt_e/T) * (mean_t probs_te)
    if (wv == 0) {
        float p[8];
        #pragma unroll
        for (int e = 0; e < 8; e++) p[e] = ppart[lane * 8 + e];
        #pragma unroll
        for (int off = 32; off > 0; off >>= 1) {
            #pragma unroll
            for (int e = 0; e < 8; e++) p[e] += __shfl_xor(p[e], off, 64);
        }
        if (lane == 0) {
            float s = 0.f;
            #pragma unroll
            for (int e = 0; e < 8; e++)
                s += ((float)fulltot[e] / (float)T_TOK) * (p[e] / (float)T_TOK);
            out_aux[0] = (float)E_EXP * s;
        }
    }
}

// ---------------- gather: x fp32 rows -> xg tiled bf16 [e][mt][kt][g][row][8] ----------------
__global__ __launch_bounds__(256) void gather_kernel(
    const float* __restrict__ x, const int* __restrict__ tok_list,
    const int* __restrict__ cnt, unsigned short* __restrict__ xg)
{
    int bid = blockIdx.x;              // 8 e * 10 mt * 4 ktg = 320
    int e   = bid / 40;
    int rem = bid % 40;
    int mt  = rem >> 2, ktg = rem & 3;
    int count = cnt[e];
    int m0 = mt * 64;
    if (m0 >= count) return;

    int tid = threadIdx.x;
    const int* tl = tok_list + e * CAP;

    #pragma unroll
    for (int kk = 0; kk < 4; kk++) {
        int kt = ktg * 4 + kk;
        unsigned short* dst = xg + XG_TILE(e, mt, kt);
        #pragma unroll
        for (int p = 0; p < 2; p++) {
            int c = tid + 256 * p;     // chunk = g*64 + row
            int g = c >> 6, row = c & 63;
            int gm = m0 + row;
            int tok = tl[gm < count ? gm : count - 1];
            const float* src = x + (size_t)tok * D_DIM + kt * 64 + g * 8;
            float4 v0 = *(const float4*)(src);
            float4 v1 = *(const float4*)(src + 4);
            short8 v;
            v[0] = f2bf(v0.x); v[1] = f2bf(v0.y); v[2] = f2bf(v0.z); v[3] = f2bf(v0.w);
            v[4] = f2bf(v1.x); v[5] = f2bf(v1.y); v[6] = f2bf(v1.z); v[7] = f2bf(v1.w);
            *(short8*)&dst[(size_t)c * 8] = v;   // coalesced
        }
    }
}

// ---------------- expert GEMM: 64x64x64 tiles, coalesced DMA from tiled images ----------------
// Each lane sources its own 16-B slice (base + lane*16); LDS dest is the wave-uniform
// plane base. One dma16 = one 1-KB fully-coalesced transaction.
__device__ inline void stage_dma(const unsigned short* gAt, const unsigned short* gBt,
                                 unsigned short (*Ab)[64][8], unsigned short (*Bb)[64][8],
                                 int w, int lane)
{
    size_t lo = (size_t)lane * 8;                          // this lane's 16-B slice
    dma16(gAt + (size_t)w * 512 + lo,       &Ab[w][0][0]);
    dma16(gAt + (size_t)(w + 4) * 512 + lo, &Ab[w + 4][0][0]);
    dma16(gBt + (size_t)w * 512 + lo,       &Bb[w][0][0]);
    dma16(gBt + (size_t)(w + 4) * 512 + lo, &Bb[w + 4][0][0]);
}

__global__ __launch_bounds__(256) void expert_gemm(
    const unsigned short* __restrict__ xg, const unsigned short* __restrict__ Wb,
    const float* __restrict__ bias,
    const int* __restrict__ tok_list, const int* __restrict__ cnt,
    const float* __restrict__ top_prob, float* __restrict__ out)
{
    int bid = blockIdx.x;
    int e   = bid / (MT * 16);
    int rem = bid % (MT * 16);
    int mt  = rem >> 4, nt = rem & 15;
    int count = cnt[e];
    int m0 = mt * 64;
    if (m0 >= count) return;
    int n0 = nt * 64;

    // [buf][plane g][row][8 bf16]: bank = row*4 mod 32 -> 2-way aliasing (free)
    __shared__ unsigned short Ab[2][8][64][8];   // 16 KB
    __shared__ unsigned short Bb[2][8][64][8];   // 16 KB

    int tid  = threadIdx.x;
    int lane = tid & 63, w = tid >> 6;
    int quad = lane >> 4, l16 = lane & 15;
    int mw = (w >> 1) * 32, nw = (w & 1) * 32;

    const int* tl = tok_list + e * CAP;
    const unsigned short* gA0 = xg + XG_TILE(e, mt, 0);
    const unsigned short* gB0 = Wb + WB_TILE(e, nt, 0);

    f32x4 acc[2][2];
    #pragma unroll
    for (int i = 0; i < 2; i++)
        #pragma unroll
        for (int j = 0; j < 2; j++)
            acc[i][j] = (f32x4){0.f, 0.f, 0.f, 0.f};

    stage_dma(gA0, gB0, Ab[0], Bb[0], w, lane);

    int cur = 0;
    #pragma unroll 1
    for (int kt = 0; kt < 16; kt++) {
        __syncthreads();                         // drains DMA for cur + LDS reuse
        if (kt + 1 < 16)
            stage_dma(gA0 + (size_t)(kt + 1) * 4096, gB0 + (size_t)(kt + 1) * 4096,
                      Ab[cur ^ 1], Bb[cur ^ 1], w, lane);

        short8 af[2][2], bf[2][2];               // [s][i]
        #pragma unroll
        for (int s = 0; s < 2; s++) {
            #pragma unroll
            for (int i = 0; i < 2; i++) {
                af[s][i] = *(const short8*)&Ab[cur][s * 4 + quad][mw + 16 * i + l16][0];
                bf[s][i] = *(const short8*)&Bb[cur][s * 4 + quad][nw + 16 * i + l16][0];
            }
        }
        #pragma unroll
        for (int s = 0; s < 2; s++)
            #pragma unroll
            for (int i = 0; i < 2; i++)
                #pragma unroll
                for (int j = 0; j < 2; j++)
                    acc[i][j] = __builtin_amdgcn_mfma_f32_16x16x32_bf16(
                        af[s][i], bf[s][j], acc[i][j], 0, 0, 0);
        cur ^= 1;
    }

    float bv[2];
    #pragma unroll
    for (int j = 0; j < 2; j++)
        bv[j] = bias[e * D_DIM + n0 + nw + 16 * j + l16];

    #pragma unroll
    for (int i = 0; i < 2; i++) {
        int rb = m0 + mw + 16 * i + quad * 4;
        #pragma unroll
        for (int r = 0; r < 4; r++) {
            int gm = rb + r;
            if (gm >= count) continue;
            int tok = tl[gm];
            float p = top_prob[tok];
            float* orow = out + (size_t)tok * D_DIM + n0 + nw + l16;
            #pragma unroll
            for (int j = 0; j < 2; j++)
                orow[16 * j] = (acc[i][j][r] + bv[j]) * p;
        }
    }
}

extern "C" void kernel_launch(void* const* d_in, const int* in_sizes, int n_in,
                              void* d_out, int out_size, void* d_ws, size_t ws_size,
                              hipStream_t stream) {
    const float* x  = (const float*)d_in[0];   // [4096,1024]
    const float* Wg = (const float*)d_in[1];   // [1024,8]
    const float* bg = (const float*)d_in[2];   // [8]
    const float* W  = (const float*)d_in[3];   // [8,1024,1024]
    const float* b  = (const float*)d_in[4];   // [8,1024]
    float* out = (float*)d_out;                // [4096*1024 + 1]

    char* ws = (char*)d_ws;                    // ~27.3 MB used
    unsigned short* Wb = (unsigned short*)(ws + 0);          // 16,777,216 B (tiled)
    unsigned short* xg = (unsigned short*)(ws + 16777216);   // 10,485,760 B (tiled)
    int*   top_idx  = (int*)(ws + 27262976);   // 16384 B
    float* top_prob = (float*)(ws + 27279360); // 16384 B
    int*   tok_list = (int*)(ws + 27295744);   // 20480 B
    int*   cnt      = (int*)(ws + 27316224);   // 32 B
    float* ppart    = (float*)(ws + 27316256); // 2048 B

    hipMemsetAsync(ppart, 0, NBIN * 8 * sizeof(float), stream);
    hipLaunchKernelGGL(prep_kernel, dim3(2048 + T_TOK / 4), dim3(256), 0, stream,
                       x, Wg, bg, W, Wb, top_idx, top_prob, ppart);
    hipLaunchKernelGGL(scan_kernel, dim3(1), dim3(1024), 0, stream,
                       top_idx, tok_list, cnt, ppart, out, out + (size_t)T_TOK * D_DIM);
    hipLaunchKernelGGL(gather_kernel, dim3(320), dim3(256), 0, stream,
                       x, tok_list, cnt, xg);
    hipLaunchKernelGGL(expert_gemm, dim3(E_EXP * MT * 16), dim3(256), 0, stream,
                       xg, Wb, b, tok_list, cnt, top_prob, out);
}